// Round 1
// baseline (488.851 us; speedup 1.0000x reference)
//
#include <hip/hip_runtime.h>

#define NN 50000
#define NE 300000

typedef _Float16 f16;
typedef _Float16 f16x4 __attribute__((ext_vector_type(4)));
typedef float f32x4 __attribute__((ext_vector_type(4)));

#define A_STRIDE 136   // 128 + 8 pad, f16 elements
#define A2_STRIDE 72   // 64 + 8 pad

__device__ __forceinline__ f16x4 cvt4(float4 v) {
    f16x4 r; r.x = (f16)v.x; r.y = (f16)v.y; r.z = (f16)v.z; r.w = (f16)v.w;
    return r;
}

// ---------------- init: h = 2*x (h lives in the d_out slice) ----------------
__global__ void init_kernel(const float* __restrict__ x, float* __restrict__ h, int n4) {
    int i = blockIdx.x * blockDim.x + threadIdx.x;
    if (i < n4) {
        float4 v = ((const float4*)x)[i];
        ((float4*)h)[i] = make_float4(2.f * v.x, 2.f * v.y, 2.f * v.z, 2.f * v.w);
    }
}

// ---------------- edge MLP + scatter-add ----------------
// per block-iter: 64 edges (4 waves x 16-edge MFMA tiles)
__global__ void edge_kernel(const float* __restrict__ x,
                            const int* __restrict__ tgt,
                            const int* __restrict__ src,
                            const float* __restrict__ attr,
                            const float* __restrict__ W,   // [128][64]
                            const float* __restrict__ b,   // [64]
                            float* __restrict__ h) {
    __shared__ f16 As[64 * A_STRIDE];
    __shared__ int tgt_s[64];
    __shared__ int src_s[64];

    const int t    = threadIdx.x;
    const int lane = t & 63;
    const int wid  = t >> 6;
    const int lr   = lane & 15;
    const int lg   = lane >> 4;

    // Preload W fragments into registers: wf[k0][n] holds W[k0*16+4*lg+j][n*16+lr]
    f16x4 wf[8][4];
#pragma unroll
    for (int k0 = 0; k0 < 8; ++k0) {
        const int kb = k0 * 16 + 4 * lg;
#pragma unroll
        for (int n = 0; n < 4; ++n) {
            const int c = n * 16 + lr;
            f16x4 w;
            w.x = (f16)W[(kb + 0) * 64 + c];
            w.y = (f16)W[(kb + 1) * 64 + c];
            w.z = (f16)W[(kb + 2) * 64 + c];
            w.w = (f16)W[(kb + 3) * 64 + c];
            wf[k0][n] = w;
        }
    }
    float bf[4];
#pragma unroll
    for (int n = 0; n < 4; ++n) bf[n] = b[n * 16 + lr];

    const float4* x4 = (const float4*)x;
    const float4* a4 = (const float4*)attr;

    const int iters = (NE + 63) >> 6;
    for (int it = blockIdx.x; it < iters; it += gridDim.x) {
        const int e0 = it << 6;
        if (t < 64) {
            int e = e0 + t;
            tgt_s[t] = (e < NE) ? tgt[e] : -1;
            src_s[t] = (e < NE) ? src[e] : 0;
        }
        __syncthreads();

        // stage A = [x[src] | attr] as f16 into LDS
        {
            const int rb = t >> 4;        // row base 0..15
            const int cq = t & 15;        // float4 column
#pragma unroll
            for (int i = 0; i < 4; ++i) {
                const int rr = rb + i * 16;
                const int s  = src_s[rr];
                float4 vx = x4[s * 16 + cq];
                *(f16x4*)&As[rr * A_STRIDE + cq * 4] = cvt4(vx);
                const int e = e0 + rr;
                float4 va = (e < NE) ? a4[(size_t)e * 16 + cq]
                                     : make_float4(0.f, 0.f, 0.f, 0.f);
                *(f16x4*)&As[rr * A_STRIDE + 64 + cq * 4] = cvt4(va);
            }
        }
        __syncthreads();

        // MFMA: wave wid owns rows [wid*16, wid*16+16)
        const int r0 = wid << 4;
        f32x4 acc[4];
#pragma unroll
        for (int n = 0; n < 4; ++n) acc[n] = (f32x4){0.f, 0.f, 0.f, 0.f};
#pragma unroll
        for (int k0 = 0; k0 < 8; ++k0) {
            f16x4 a = *(const f16x4*)&As[(r0 + lr) * A_STRIDE + k0 * 16 + 4 * lg];
#pragma unroll
            for (int n = 0; n < 4; ++n)
                acc[n] = __builtin_amdgcn_mfma_f32_16x16x16f16(a, wf[k0][n], acc[n], 0, 0, 0);
        }

        // bias + relu + atomic scatter
#pragma unroll
        for (int n = 0; n < 4; ++n) {
#pragma unroll
            for (int j = 0; j < 4; ++j) {
                const int r  = 4 * lg + j;
                const int tg = tgt_s[r0 + r];
                float v = acc[n][j] + bf[n];
                v = v > 0.f ? v : 0.f;
                if (tg >= 0) unsafeAtomicAdd(&h[(size_t)tg * 64 + n * 16 + lr], v);
            }
        }
        __syncthreads();
    }
}

// ---------------- node MLP (in place on d_out slice) ----------------
__global__ void node_kernel(float* __restrict__ io,
                            const float* __restrict__ W1, const float* __restrict__ b1,
                            const float* __restrict__ W2, const float* __restrict__ b2) {
    __shared__ f16 As[64 * A2_STRIDE];

    const int t    = threadIdx.x;
    const int lane = t & 63;
    const int wid  = t >> 6;
    const int lr   = lane & 15;
    const int lg   = lane >> 4;

    f16x4 w1f[4][4], w2f[4][4];
#pragma unroll
    for (int k0 = 0; k0 < 4; ++k0) {
        const int kb = k0 * 16 + 4 * lg;
#pragma unroll
        for (int n = 0; n < 4; ++n) {
            const int c = n * 16 + lr;
            f16x4 w;
            w.x = (f16)W1[(kb + 0) * 64 + c];
            w.y = (f16)W1[(kb + 1) * 64 + c];
            w.z = (f16)W1[(kb + 2) * 64 + c];
            w.w = (f16)W1[(kb + 3) * 64 + c];
            w1f[k0][n] = w;
            w.x = (f16)W2[(kb + 0) * 64 + c];
            w.y = (f16)W2[(kb + 1) * 64 + c];
            w.z = (f16)W2[(kb + 2) * 64 + c];
            w.w = (f16)W2[(kb + 3) * 64 + c];
            w2f[k0][n] = w;
        }
    }
    float b1f[4], b2f[4];
#pragma unroll
    for (int n = 0; n < 4; ++n) {
        b1f[n] = b1[n * 16 + lr];
        b2f[n] = b2[n * 16 + lr];
    }

    const float4* io4 = (const float4*)io;
    const int iters = (NN + 63) >> 6;
    for (int it = blockIdx.x; it < iters; it += gridDim.x) {
        const int n0 = it << 6;
        {
            const int rb = t >> 4;
            const int cq = t & 15;
#pragma unroll
            for (int i = 0; i < 4; ++i) {
                const int rr   = rb + i * 16;
                const int node = n0 + rr;
                float4 v = (node < NN) ? io4[(size_t)node * 16 + cq]
                                       : make_float4(0.f, 0.f, 0.f, 0.f);
                *(f16x4*)&As[rr * A2_STRIDE + cq * 4] = cvt4(v);
            }
        }
        __syncthreads();

        const int r0 = wid << 4;
        f32x4 acc[4];
#pragma unroll
        for (int n = 0; n < 4; ++n) acc[n] = (f32x4){0.f, 0.f, 0.f, 0.f};
#pragma unroll
        for (int k0 = 0; k0 < 4; ++k0) {
            f16x4 a = *(const f16x4*)&As[(r0 + lr) * A2_STRIDE + k0 * 16 + 4 * lg];
#pragma unroll
            for (int n = 0; n < 4; ++n)
                acc[n] = __builtin_amdgcn_mfma_f32_16x16x16f16(a, w1f[k0][n], acc[n], 0, 0, 0);
        }
        // y1 = relu(acc + b1) written back (transposed to A-layout); same-wave rows only,
        // LDS ops within a wave are in order -> no barrier needed
#pragma unroll
        for (int n = 0; n < 4; ++n) {
#pragma unroll
            for (int j = 0; j < 4; ++j) {
                const int r = 4 * lg + j;
                float v = acc[n][j] + b1f[n];
                v = v > 0.f ? v : 0.f;
                As[(r0 + r) * A2_STRIDE + n * 16 + lr] = (f16)v;
            }
        }
        f32x4 acc2[4];
#pragma unroll
        for (int n = 0; n < 4; ++n) acc2[n] = (f32x4){0.f, 0.f, 0.f, 0.f};
#pragma unroll
        for (int k0 = 0; k0 < 4; ++k0) {
            f16x4 a = *(const f16x4*)&As[(r0 + lr) * A2_STRIDE + k0 * 16 + 4 * lg];
#pragma unroll
            for (int n = 0; n < 4; ++n)
                acc2[n] = __builtin_amdgcn_mfma_f32_16x16x16f16(a, w2f[k0][n], acc2[n], 0, 0, 0);
        }
#pragma unroll
        for (int n = 0; n < 4; ++n) {
#pragma unroll
            for (int j = 0; j < 4; ++j) {
                const int r    = 4 * lg + j;
                const int node = n0 + r0 + r;
                float v = acc2[n][j] + b2f[n];
                v = v > 0.f ? v : 0.f;
                if (node < NN) io[(size_t)node * 64 + n * 16 + lr] = v;
            }
        }
        __syncthreads();
    }
}

extern "C" void kernel_launch(void* const* d_in, const int* in_sizes, int n_in,
                              void* d_out, int out_size, void* d_ws, size_t ws_size,
                              hipStream_t stream) {
    (void)in_sizes; (void)n_in; (void)d_ws; (void)ws_size; (void)out_size;

    const float* W_up   = (const float*)d_in[15];
    const float* b_up   = (const float*)d_in[16];
    const float* W_down = (const float*)d_in[17];
    const float* b_down = (const float*)d_in[18];
    const float* W1     = (const float*)d_in[19];
    const float* b1     = (const float*)d_in[20];
    const float* W2     = (const float*)d_in[21];
    const float* b2     = (const float*)d_in[22];

    for (int d = 0; d < 3; ++d) {
        const float* x  = (const float*)d_in[5 * d + 0];
        const int*   ui = (const int*)  d_in[5 * d + 1];
        const int*   di = (const int*)  d_in[5 * d + 2];
        const float* ua = (const float*)d_in[5 * d + 3];
        const float* da = (const float*)d_in[5 * d + 4];
        float* h = (float*)d_out + (size_t)d * NN * 64;

        init_kernel<<<(NN * 16 + 255) / 256, 256, 0, stream>>>(x, h, NN * 16);
        edge_kernel<<<1024, 256, 0, stream>>>(x, ui, ui + NE, ua, W_up, b_up, h);
        edge_kernel<<<1024, 256, 0, stream>>>(x, di, di + NE, da, W_down, b_down, h);
        node_kernel<<<782, 256, 0, stream>>>(h, W1, b1, W2, b2);
    }
}